// Round 2
// 768.449 us; speedup vs baseline: 1.1038x; 1.1038x over previous
//
#include <hip/hip_runtime.h>

#define B_SZ 8192
#define M_SZ 256
#define N_SZ 512
#define TB 32
#define THREADS 1024
#define NITER 16

typedef _Float16 half8 __attribute__((ext_vector_type(8)));
typedef float floatx4 __attribute__((ext_vector_type(4)));

// ---- f16 conversions of D, D^T, W ----
__global__ void conv_kernel(const float* __restrict__ W, const float* __restrict__ D,
                            _Float16* __restrict__ Wf, _Float16* __restrict__ Df,
                            _Float16* __restrict__ Dtf) {
  int i = blockIdx.x * blockDim.x + threadIdx.x;
  if (i < N_SZ * N_SZ) {
    float d = D[i];
    Df[i] = (_Float16)d;
    int r = i >> 9;
    int c = i & (N_SZ - 1);
    Dtf[c * N_SZ + r] = (_Float16)d;
  }
  if (i < N_SZ * M_SZ) Wf[i] = (_Float16)W[i];
}

// ---- E = D @ S  (fp32 accumulate, f16 output); D via uniform (scalar) loads ----
__global__ __launch_bounds__(512) void ecomp_kernel(const float* __restrict__ S,
                                                    const float* __restrict__ D,
                                                    _Float16* __restrict__ Ef) {
  const int tid = threadIdx.x;          // column 0..511
  const int r0 = blockIdx.x * 2;        // 256 blocks x 2 rows
  float a0 = 0.f, a1 = 0.f;
#pragma unroll 8
  for (int j = 0; j < N_SZ; ++j) {
    float s = S[(size_t)j * N_SZ + tid];
    a0 += D[(size_t)r0 * N_SZ + j] * s;        // uniform -> s_load
    a1 += D[(size_t)(r0 + 1) * N_SZ + j] * s;  // uniform -> s_load
  }
  Ef[(size_t)r0 * N_SZ + tid] = (_Float16)a0;
  Ef[(size_t)(r0 + 1) * N_SZ + tid] = (_Float16)a1;
}

// LDS layout: two 32x512 f16 buffers, row stride 1024 B.
// XOR swizzle: element (row,col) at byte  row*1024 + (((col>>3) ^ (row&7))<<4) + (col&7)*2
__global__ __launch_bounds__(THREADS, 4) void ista_kernel(
    const float* __restrict__ y, const _Float16* __restrict__ Ef,
    const _Float16* __restrict__ Df, const _Float16* __restrict__ Dtf,
    const _Float16* __restrict__ Wf, const float* __restrict__ thrp,
    float* __restrict__ out) {
  __shared__ _Float16 lds[2 * TB * N_SZ];  // 64 KB
  char* const ldsb = reinterpret_cast<char*>(lds);
  constexpr int BOFF = TB * N_SZ * 2;  // byte offset of bufB

  const int tid = threadIdx.x;
  const int w = tid >> 6;      // 0..15, wave = one 32-col panel
  const int lane = tid & 63;
  const int m16 = lane & 15;
  const int q = lane >> 4;     // 0..3
  const int x8 = m16 & 7;
  const int rowBase = blockIdx.x * TB;

  // Per-lane swizzled 16B-group byte offsets for A-fragment reads.
  // group(ks) = (ks*4+q) ^ x8 ;  byte = (ks>>1)*128 + offE/offO
  const int offE = (((x8 & 4) >> 2) << 6) | ((q ^ (x8 & 3)) << 4);
  const int offO = offE ^ 64;

  floatx4 acc[2][2];

  // ---- stage y rows -> bufA region (32 x 256 f16, row stride 512 B, same XOR) ----
  {
    const int r = tid >> 5;   // 0..31
    const int g = tid & 31;   // 16B group = 8 cols
    const float* src = y + (size_t)(rowBase + r) * M_SZ + g * 8;
    float4 v0 = *reinterpret_cast<const float4*>(src);
    float4 v1 = *reinterpret_cast<const float4*>(src + 4);
    half8 h = {(_Float16)v0.x, (_Float16)v0.y, (_Float16)v0.z, (_Float16)v0.w,
               (_Float16)v1.x, (_Float16)v1.y, (_Float16)v1.z, (_Float16)v1.w};
    *reinterpret_cast<half8*>(ldsb + r * 512 + ((g ^ (r & 7)) << 4)) = h;
  }
  __syncthreads();

#define ZACC()                                                        \
  acc[0][0] = acc[0][1] = acc[1][0] = acc[1][1] = (floatx4){0.f, 0.f, 0.f, 0.f}

  // ---- Wy = y @ W^T (K=256) ----
  ZACC();
  {
    const char* a0p = ldsb + m16 * 512;
    const char* a1p = ldsb + (16 + m16) * 512;
    const _Float16* b0p = Wf + (size_t)(w * 32 + m16) * M_SZ + q * 8;
    const _Float16* b1p = b0p + 16 * M_SZ;
#pragma unroll 2
    for (int ks = 0; ks < 8; ++ks) {
      const int go = ((ks & 1) ? offO : offE) + (ks >> 1) * 128;
      half8 a0 = *reinterpret_cast<const half8*>(a0p + go);
      half8 a1 = *reinterpret_cast<const half8*>(a1p + go);
      half8 b0 = *reinterpret_cast<const half8*>(b0p + ks * 32);
      half8 b1 = *reinterpret_cast<const half8*>(b1p + ks * 32);
      acc[0][0] = __builtin_amdgcn_mfma_f32_16x16x32_f16(a0, b0, acc[0][0], 0, 0, 0);
      acc[0][1] = __builtin_amdgcn_mfma_f32_16x16x32_f16(a0, b1, acc[0][1], 0, 0, 0);
      acc[1][0] = __builtin_amdgcn_mfma_f32_16x16x32_f16(a1, b0, acc[1][0], 0, 0, 0);
      acc[1][1] = __builtin_amdgcn_mfma_f32_16x16x32_f16(a1, b1, acc[1][1], 0, 0, 0);
    }
  }
  // write Wy -> bufB (swizzled f16)
#pragma unroll
  for (int rt = 0; rt < 2; ++rt)
#pragma unroll
    for (int ct = 0; ct < 2; ++ct)
#pragma unroll
      for (int r = 0; r < 4; ++r) {
        const int row = rt * 16 + q * 4 + r;
        const int col = w * 32 + ct * 16 + m16;
        *reinterpret_cast<_Float16*>(
            ldsb + BOFF + row * 1024 +
            ((((col >> 3) ^ (row & 7)) << 4) | ((col & 7) << 1))) = (_Float16)acc[rt][ct][r];
      }
  __syncthreads();

  // K=512 GEMM: A from swizzled LDS, B rows from global (L2-hot)
  auto gemm512 = [&](const int aoff, const _Float16* __restrict__ Bmat) {
    const char* ap = ldsb + aoff + m16 * 1024;
    const _Float16* b0p = Bmat + (size_t)(w * 32 + m16) * N_SZ + q * 8;
    const _Float16* b1p = b0p + 16 * N_SZ;
#pragma unroll 2
    for (int ks = 0; ks < 16; ++ks) {
      const int go = ((ks & 1) ? offO : offE) + (ks >> 1) * 128;
      half8 a0 = *reinterpret_cast<const half8*>(ap + go);
      half8 a1 = *reinterpret_cast<const half8*>(ap + 16 * 1024 + go);
      half8 b0 = *reinterpret_cast<const half8*>(b0p + ks * 32);
      half8 b1 = *reinterpret_cast<const half8*>(b1p + ks * 32);
      acc[0][0] = __builtin_amdgcn_mfma_f32_16x16x32_f16(a0, b0, acc[0][0], 0, 0, 0);
      acc[0][1] = __builtin_amdgcn_mfma_f32_16x16x32_f16(a0, b1, acc[0][1], 0, 0, 0);
      acc[1][0] = __builtin_amdgcn_mfma_f32_16x16x32_f16(a1, b0, acc[1][0], 0, 0, 0);
      acc[1][1] = __builtin_amdgcn_mfma_f32_16x16x32_f16(a1, b1, acc[1][1], 0, 0, 0);
    }
  };

  // ---- c = Wy @ D^T (K=512), kept in f16 registers ----
  ZACC();
  gemm512(BOFF, Df);
  _Float16 ch[2][2][4];
#pragma unroll
  for (int rt = 0; rt < 2; ++rt)
#pragma unroll
    for (int ct = 0; ct < 2; ++ct)
#pragma unroll
      for (int r = 0; r < 4; ++r) ch[rt][ct][r] = (_Float16)acc[rt][ct][r];

  // ---- out slice 0 = 0 (d0) ----
  {
    floatx4 z4 = {0.f, 0.f, 0.f, 0.f};
    floatx4* o4 = reinterpret_cast<floatx4*>(out + (size_t)rowBase * N_SZ);
#pragma unroll
    for (int i = 0; i < (TB * N_SZ / 4) / THREADS; ++i)
      __builtin_nontemporal_store(z4, o4 + tid + i * THREADS);
  }
  __syncthreads();  // all waves done reading bufB (Wy) in c-GEMM

  const float thrv = *thrp;

  // ---- s1 = soft_thr(c) -> bufB  (d0 = 0, so iteration-1 GEMM1 is skipped) ----
#pragma unroll
  for (int rt = 0; rt < 2; ++rt)
#pragma unroll
    for (int ct = 0; ct < 2; ++ct)
#pragma unroll
      for (int r = 0; r < 4; ++r) {
        float u = (float)ch[rt][ct][r];
        float s = fmaxf(u - thrv, 0.f) - fmaxf(-u - thrv, 0.f);
        const int row = rt * 16 + q * 4 + r;
        const int col = w * 32 + ct * 16 + m16;
        *reinterpret_cast<_Float16*>(
            ldsb + BOFF + row * 1024 +
            ((((col >> 3) ^ (row & 7)) << 4) | ((col & 7) << 1))) = (_Float16)s;
      }
  __syncthreads();

#pragma unroll 1
  for (int it = 1; it <= NITER; ++it) {
    // ---- d_it = s_it @ D : out from f32 acc (nt), f16 copy -> bufA for next GEMM1
    ZACC();
    gemm512(BOFF, Dtf);
    float* osl = out + ((size_t)it * B_SZ + rowBase) * N_SZ;
#pragma unroll
    for (int rt = 0; rt < 2; ++rt)
#pragma unroll
      for (int ct = 0; ct < 2; ++ct)
#pragma unroll
        for (int r = 0; r < 4; ++r) {
          float dv = acc[rt][ct][r];
          const int row = rt * 16 + q * 4 + r;
          const int col = w * 32 + ct * 16 + m16;
          __builtin_nontemporal_store(dv, osl + (size_t)row * N_SZ + col);
          *reinterpret_cast<_Float16*>(
              ldsb + row * 1024 +
              ((((col >> 3) ^ (row & 7)) << 4) | ((col & 7) << 1))) = (_Float16)dv;
        }
    __syncthreads();
    if (it == NITER) break;

    // ---- u = d @ E^T + c ; s = soft_thr(u) -> bufB ----
    ZACC();
    gemm512(0, Ef);
#pragma unroll
    for (int rt = 0; rt < 2; ++rt)
#pragma unroll
      for (int ct = 0; ct < 2; ++ct)
#pragma unroll
        for (int r = 0; r < 4; ++r) {
          float u = acc[rt][ct][r] + (float)ch[rt][ct][r];
          float s = fmaxf(u - thrv, 0.f) - fmaxf(-u - thrv, 0.f);
          const int row = rt * 16 + q * 4 + r;
          const int col = w * 32 + ct * 16 + m16;
          *reinterpret_cast<_Float16*>(
              ldsb + BOFF + row * 1024 +
              ((((col >> 3) ^ (row & 7)) << 4) | ((col & 7) << 1))) = (_Float16)s;
        }
    __syncthreads();
  }
#undef ZACC
}

extern "C" void kernel_launch(void* const* d_in, const int* in_sizes, int n_in,
                              void* d_out, int out_size, void* d_ws, size_t ws_size,
                              hipStream_t stream) {
  const float* y = (const float*)d_in[0];
  const float* S = (const float*)d_in[1];
  const float* W = (const float*)d_in[2];
  const float* D = (const float*)d_in[3];
  const float* thr = (const float*)d_in[4];
  float* out = (float*)d_out;

  char* ws = (char*)d_ws;
  _Float16* Ef = (_Float16*)(ws);
  _Float16* Df = (_Float16*)(ws + 512 * 1024);
  _Float16* Dtf = (_Float16*)(ws + 1024 * 1024);
  _Float16* Wf = (_Float16*)(ws + 1536 * 1024);

  conv_kernel<<<(N_SZ * N_SZ + 255) / 256, 256, 0, stream>>>(W, D, Wf, Df, Dtf);
  ecomp_kernel<<<N_SZ / 2, 512, 0, stream>>>(S, D, Ef);
  ista_kernel<<<B_SZ / TB, THREADS, 0, stream>>>(y, Ef, Df, Dtf, Wf, thr, out);
}